// Round 4
// baseline (53.807 us; speedup 1.0000x reference)
//
#include <hip/hip_runtime.h>

typedef unsigned short u16;
typedef float f32x4 __attribute__((ext_vector_type(4)));
typedef short bf16x8 __attribute__((ext_vector_type(8)));

constexpr int Bn = 4, Ln = 512, Mn = 32, EMBn = 512, Hn = 8, HSn = 64;
constexpr int Rn = Mn * Hn; // 256

__device__ __forceinline__ float wave_sum(float v) {
#pragma unroll
  for (int off = 1; off < 64; off <<= 1) v += __shfl_xor(v, off, 64);
  return v;
}
__device__ __forceinline__ u16 f2bf(float f) {
  unsigned u = __float_as_uint(f);
  unsigned r = (u + 0x7FFFu + ((u >> 16) & 1u)) >> 16;
  return (u16)r;
}
__device__ __forceinline__ unsigned pack2(float a, float b) {
  return (unsigned)f2bf(a) | ((unsigned)f2bf(b) << 16);
}

// ---------------------------------------------------------------------------
// K1: blocks [0,512): LayerNorm -> h_bf16. blocks [512,768): P = cells*q_w.
// ---------------------------------------------------------------------------
__global__ __launch_bounds__(256) void ln_pproj_kernel(
    const float* __restrict__ x, const float* __restrict__ gam,
    const float* __restrict__ bet, const float* __restrict__ cells,
    const float* __restrict__ q_w, const float* __restrict__ q_b,
    u16* __restrict__ hb, u16* __restrict__ Pb, float* __restrict__ pb) {
  int bid = blockIdx.x, tid = threadIdx.x;
  __shared__ float cs[HSn];
  if (bid < 512) {
    int row = bid * 4 + (tid >> 6), lane = tid & 63;
    const float* xr = x + (size_t)row * EMBn + lane * 8;
    float4 a0 = *(const float4*)xr;
    float4 a1 = *(const float4*)(xr + 4);
    float s = a0.x + a0.y + a0.z + a0.w + a1.x + a1.y + a1.z + a1.w;
    float ss = a0.x * a0.x + a0.y * a0.y + a0.z * a0.z + a0.w * a0.w +
               a1.x * a1.x + a1.y * a1.y + a1.z * a1.z + a1.w * a1.w;
    s = wave_sum(s);
    ss = wave_sum(ss);
    float mu = s * (1.0f / EMBn);
    float var = ss * (1.0f / EMBn) - mu * mu;
    float rstd = rsqrtf(var + 1e-5f);
    const float* gp = gam + lane * 8;
    const float* bp = bet + lane * 8;
    float4 g0 = *(const float4*)gp, g1 = *(const float4*)(gp + 4);
    float4 b0 = *(const float4*)bp, b1 = *(const float4*)(bp + 4);
    float4 o0, o1;
    o0.x = (a0.x - mu) * rstd * g0.x + b0.x;
    o0.y = (a0.y - mu) * rstd * g0.y + b0.y;
    o0.z = (a0.z - mu) * rstd * g0.z + b0.z;
    o0.w = (a0.w - mu) * rstd * g0.w + b0.w;
    o1.x = (a1.x - mu) * rstd * g1.x + b1.x;
    o1.y = (a1.y - mu) * rstd * g1.y + b1.y;
    o1.z = (a1.z - mu) * rstd * g1.z + b1.z;
    o1.w = (a1.w - mu) * rstd * g1.w + b1.w;
    uint4 st;
    st.x = pack2(o0.x, o0.y);
    st.y = pack2(o0.z, o0.w);
    st.z = pack2(o1.x, o1.y);
    st.w = pack2(o1.z, o1.w);
    *(uint4*)&hb[(size_t)row * EMBn + lane * 8] = st;
  } else {
    int r = bid - 512;
    int hh = r & 7;
    if (tid < HSn) cs[tid] = cells[(size_t)r * HSn + tid];
    __syncthreads();
    for (int e = tid; e < EMBn; e += 256) {
      float acc = 0.f;
#pragma unroll 8
      for (int s2 = 0; s2 < HSn; ++s2)
        acc += cs[s2] * q_w[(size_t)(hh * HSn + s2) * EMBn + e];
      Pb[(size_t)r * EMBn + e] = f2bf(acc);
    }
    if (tid == 0) {
      float a = 0.f;
      for (int s2 = 0; s2 < HSn; ++s2) a += cs[s2] * q_b[hh * HSn + s2];
      pb[r] = a;
    }
  }
}

// ---------------------------------------------------------------------------
// K2: blocks [0,64): fused score+softmax -> Wb bf16.
//   Block (b, 16 rows r). 8 waves; wave w covers l-span [w*64, w*64+64).
//   Direct-from-global MFMA (operands L2-resident), no staging, no barriers
//   in the GEMM loop. Cross-wave softmax stats via tiny LDS.
// blocks [64,320): transpose h -> htb[b][j][l] for K3's A operand.
// ---------------------------------------------------------------------------
__global__ __launch_bounds__(512) void score_sm_trans_kernel(
    const u16* __restrict__ hb, const u16* __restrict__ Pb,
    const float* __restrict__ pb, u16* __restrict__ htb,
    u16* __restrict__ Wb) {
  __shared__ float smax[16][8];
  __shared__ float ssum[16][8];
  __shared__ u16 ts[64][65];
  int bid = blockIdx.x, tid = threadIdx.x;
  int w = tid >> 6, lane = tid & 63;
  if (bid < 64) {
    int b = bid >> 4, r0 = (bid & 15) * 16;
    const int lr = lane & 15, lg = lane >> 4;
    const u16* Ab = Pb + (size_t)(r0 + lr) * 512 + lg * 8;
    const u16* Bb = hb + ((size_t)b * Ln + w * 64 + lr) * 512 + lg * 8;
    f32x4 acc0 = {0.f, 0.f, 0.f, 0.f};
    f32x4 acc1 = {0.f, 0.f, 0.f, 0.f};
    f32x4 acc2 = {0.f, 0.f, 0.f, 0.f};
    f32x4 acc3 = {0.f, 0.f, 0.f, 0.f};
    bf16x8 ac = *(const bf16x8*)Ab;
    bf16x8 b0 = *(const bf16x8*)Bb;
    bf16x8 b1 = *(const bf16x8*)(Bb + 16 * 512);
    bf16x8 b2 = *(const bf16x8*)(Bb + 32 * 512);
    bf16x8 b3 = *(const bf16x8*)(Bb + 48 * 512);
#pragma unroll
    for (int c = 0; c < 16; ++c) {
      bf16x8 an, n0, n1, n2, n3;
      if (c < 15) {
        an = *(const bf16x8*)(Ab + (c + 1) * 32);
        n0 = *(const bf16x8*)(Bb + (c + 1) * 32);
        n1 = *(const bf16x8*)(Bb + 16 * 512 + (c + 1) * 32);
        n2 = *(const bf16x8*)(Bb + 32 * 512 + (c + 1) * 32);
        n3 = *(const bf16x8*)(Bb + 48 * 512 + (c + 1) * 32);
      }
      acc0 = __builtin_amdgcn_mfma_f32_16x16x32_bf16(ac, b0, acc0, 0, 0, 0);
      acc1 = __builtin_amdgcn_mfma_f32_16x16x32_bf16(ac, b1, acc1, 0, 0, 0);
      acc2 = __builtin_amdgcn_mfma_f32_16x16x32_bf16(ac, b2, acc2, 0, 0, 0);
      acc3 = __builtin_amdgcn_mfma_f32_16x16x32_bf16(ac, b3, acc3, 0, 0, 0);
      if (c < 15) {
        ac = an; b0 = n0; b1 = n1; b2 = n2; b3 = n3;
      }
    }
    // bias + scale; sv[nt][i], row r = r0 + lg*4 + i, col l = w*64+nt*16+lr
    float sv[4][4];
    float pbv[4];
#pragma unroll
    for (int i = 0; i < 4; ++i) pbv[i] = pb[r0 + lg * 4 + i];
#pragma unroll
    for (int i = 0; i < 4; ++i) {
      sv[0][i] = (acc0[i] + pbv[i]) * 0.125f;
      sv[1][i] = (acc1[i] + pbv[i]) * 0.125f;
      sv[2][i] = (acc2[i] + pbv[i]) * 0.125f;
      sv[3][i] = (acc3[i] + pbv[i]) * 0.125f;
    }
    // per-row max over this wave's 64 l
    float mx[4];
#pragma unroll
    for (int i = 0; i < 4; ++i) {
      mx[i] = fmaxf(fmaxf(sv[0][i], sv[1][i]), fmaxf(sv[2][i], sv[3][i]));
#pragma unroll
      for (int off = 1; off < 16; off <<= 1)
        mx[i] = fmaxf(mx[i], __shfl_xor(mx[i], off, 64));
    }
    if (lr == 0) {
#pragma unroll
      for (int i = 0; i < 4; ++i) smax[lg * 4 + i][w] = mx[i];
    }
    __syncthreads();
    float m[4];
#pragma unroll
    for (int i = 0; i < 4; ++i) {
      float mm = smax[lg * 4 + i][0];
#pragma unroll
      for (int ww = 1; ww < 8; ++ww) mm = fmaxf(mm, smax[lg * 4 + i][ww]);
      m[i] = mm;
    }
    float e[4][4];
    float s[4];
#pragma unroll
    for (int i = 0; i < 4; ++i) {
      e[0][i] = __expf(sv[0][i] - m[i]);
      e[1][i] = __expf(sv[1][i] - m[i]);
      e[2][i] = __expf(sv[2][i] - m[i]);
      e[3][i] = __expf(sv[3][i] - m[i]);
      s[i] = e[0][i] + e[1][i] + e[2][i] + e[3][i];
#pragma unroll
      for (int off = 1; off < 16; off <<= 1) s[i] += __shfl_xor(s[i], off, 64);
    }
    if (lr == 0) {
#pragma unroll
      for (int i = 0; i < 4; ++i) ssum[lg * 4 + i][w] = s[i];
    }
    __syncthreads();
    float inv[4];
#pragma unroll
    for (int i = 0; i < 4; ++i) {
      float tt = ssum[lg * 4 + i][0];
#pragma unroll
      for (int ww = 1; ww < 8; ++ww) tt += ssum[lg * 4 + i][ww];
      inv[i] = 1.0f / tt;
    }
#pragma unroll
    for (int nt = 0; nt < 4; ++nt) {
#pragma unroll
      for (int i = 0; i < 4; ++i) {
        size_t idx = ((size_t)b * Rn + r0 + lg * 4 + i) * 512 + w * 64 +
                     nt * 16 + lr;
        Wb[idx] = f2bf(e[nt][i] * inv[i]);
      }
    }
  } else {
    int t = bid - 64;
    int b = t >> 6, rem = t & 63;
    int l0 = (rem >> 3) * 64, j0 = (rem & 7) * 64;
#pragma unroll
    for (int i = 0; i < 2; ++i) {
      int idx = tid + i * 512;
      int row = idx >> 4, c4 = (idx & 15) * 4;
      uint2 u = *(const uint2*)&hb[(size_t)(b * Ln + l0 + row) * EMBn + j0 + c4];
      ts[row][c4] = (u16)(u.x & 0xffffu);
      ts[row][c4 + 1] = (u16)(u.x >> 16);
      ts[row][c4 + 2] = (u16)(u.y & 0xffffu);
      ts[row][c4 + 3] = (u16)(u.y >> 16);
    }
    __syncthreads();
#pragma unroll
    for (int i = 0; i < 2; ++i) {
      int idx = tid + i * 512;
      int jr = idx >> 4, lc4 = (idx & 15) * 4;
      unsigned lo = (unsigned)ts[lc4][jr] | ((unsigned)ts[lc4 + 1][jr] << 16);
      unsigned hi = (unsigned)ts[lc4 + 2][jr] | ((unsigned)ts[lc4 + 3][jr] << 16);
      uint2 u;
      u.x = lo;
      u.y = hi;
      *(uint2*)&htb[(size_t)(b * EMBn + j0 + jr) * Ln + l0 + lc4] = u;
    }
  }
}

// ---------------------------------------------------------------------------
// K3: G[b][r][j] = sum_l W[b][r][l] * ht[b][j][l].
// Direct-global MFMA with A=ht (M=j), B=W (N=r); per-wave LDS transpose of
// the C fragments so G is written coalesced in [b][r][j] layout.
// grid = 128 blocks (b x 4 rblk x 8 jblk), 256 thr; wave tile 32j x 32r.
// ---------------------------------------------------------------------------
__global__ __launch_bounds__(256) void gmat_kernel(
    const u16* __restrict__ htb, const u16* __restrict__ Wb,
    float* __restrict__ G) {
  __shared__ float tl[4][32][40];
  int bid = blockIdx.x, tid = threadIdx.x;
  int b = bid >> 5, rem = bid & 31;
  int rblk = rem >> 3, jblk = rem & 7;
  int w = tid >> 6, lane = tid & 63;
  int wj = w >> 1, wr = w & 1;
  int j0 = jblk * 64 + wj * 32, r0 = rblk * 64 + wr * 32;
  const int lr = lane & 15, lg = lane >> 4;
  const u16* A0 = htb + ((size_t)b * EMBn + j0 + lr) * Ln + lg * 8;
  const u16* A1 = A0 + 16 * Ln;
  const u16* B0 = Wb + ((size_t)b * Rn + r0 + lr) * Ln + lg * 8;
  const u16* B1 = B0 + 16 * Ln;
  f32x4 acc00 = {0.f, 0.f, 0.f, 0.f};
  f32x4 acc01 = {0.f, 0.f, 0.f, 0.f};
  f32x4 acc10 = {0.f, 0.f, 0.f, 0.f};
  f32x4 acc11 = {0.f, 0.f, 0.f, 0.f};
  bf16x8 a0 = *(const bf16x8*)A0;
  bf16x8 a1 = *(const bf16x8*)A1;
  bf16x8 b0 = *(const bf16x8*)B0;
  bf16x8 b1 = *(const bf16x8*)B1;
#pragma unroll
  for (int c = 0; c < 16; ++c) {
    bf16x8 na0, na1, nb0, nb1;
    if (c < 15) {
      na0 = *(const bf16x8*)(A0 + (c + 1) * 32);
      na1 = *(const bf16x8*)(A1 + (c + 1) * 32);
      nb0 = *(const bf16x8*)(B0 + (c + 1) * 32);
      nb1 = *(const bf16x8*)(B1 + (c + 1) * 32);
    }
    acc00 = __builtin_amdgcn_mfma_f32_16x16x32_bf16(a0, b0, acc00, 0, 0, 0);
    acc01 = __builtin_amdgcn_mfma_f32_16x16x32_bf16(a0, b1, acc01, 0, 0, 0);
    acc10 = __builtin_amdgcn_mfma_f32_16x16x32_bf16(a1, b0, acc10, 0, 0, 0);
    acc11 = __builtin_amdgcn_mfma_f32_16x16x32_bf16(a1, b1, acc11, 0, 0, 0);
    if (c < 15) {
      a0 = na0; a1 = na1; b0 = nb0; b1 = nb1;
    }
  }
  // C frag: row j' = mt*16 + lg*4 + i, col r' = nt*16 + lr
  float(*t)[40] = tl[w];
  *(f32x4*)&t[lr][lg * 4] = acc00;        // mt0 nt0
  *(f32x4*)&t[16 + lr][lg * 4] = acc01;   // mt0 nt1
  *(f32x4*)&t[lr][16 + lg * 4] = acc10;   // mt1 nt0
  *(f32x4*)&t[16 + lr][16 + lg * 4] = acc11;
  __syncthreads();
  int rr = lane >> 1, jh = lane & 1;
  float* gp = G + ((size_t)b * Rn + r0 + rr) * EMBn + j0 + jh * 16;
  const float* tp = &t[rr][jh * 16];
#pragma unroll
  for (int k = 0; k < 4; ++k) {
    *(float4*)(gp + k * 4) = *(const float4*)(tp + k * 4);
  }
}

// ---------------------------------------------------------------------------
// K4: out[b,(m,h),s] = dot(v[m, h*64+s, :], G[b, r, :]) + vb[m, h*64+s]
// ---------------------------------------------------------------------------
__global__ __launch_bounds__(256) void out_kernel(
    const float* __restrict__ v, const float* __restrict__ vb,
    const float* __restrict__ G, float* __restrict__ out) {
  int bid = blockIdx.x;
  int sc = bid & 3, hh = (bid >> 2) & 7, m = bid >> 5;
  int r = m * Hn + hh;
  __shared__ float Gs[Bn][EMBn]; // 8 KiB
  int tid = threadIdx.x;
#pragma unroll
  for (int i = 0; i < 2; ++i) {
    int idx4 = tid + i * 256;
    int bb = idx4 >> 7, e4 = (idx4 & 127) << 2;
    *(float4*)&Gs[bb][e4] = *(const float4*)&G[((size_t)bb * Rn + r) * EMBn + e4];
  }
  __syncthreads();
  int wid = tid >> 6, lane = tid & 63;
#pragma unroll
  for (int i = 0; i < 4; ++i) {
    int rr = sc * 16 + wid * 4 + i;
    const float* vr = v + ((size_t)m * EMBn + hh * HSn + rr) * EMBn + lane * 8;
    float4 v0 = *(const float4*)vr;
    float4 v1 = *(const float4*)(vr + 4);
    float acc[Bn];
#pragma unroll
    for (int bb = 0; bb < Bn; ++bb) {
      const float* gp = &Gs[bb][lane * 8];
      float4 g0 = *(const float4*)gp;
      float4 g1 = *(const float4*)(gp + 4);
      acc[bb] = v0.x * g0.x + v0.y * g0.y + v0.z * g0.z + v0.w * g0.w +
                v1.x * g1.x + v1.y * g1.y + v1.z * g1.z + v1.w * g1.w;
    }
#pragma unroll
    for (int off = 1; off < 64; off <<= 1) {
#pragma unroll
      for (int bb = 0; bb < Bn; ++bb) acc[bb] += __shfl_xor(acc[bb], off, 64);
    }
    if (lane == 0) {
      float vbv = vb[(size_t)m * EMBn + hh * HSn + rr];
#pragma unroll
      for (int bb = 0; bb < Bn; ++bb) {
        out[(((size_t)bb * Hn + hh) * Mn + m) * HSn + rr] = acc[bb] + vbv;
      }
    }
  }
}

extern "C" void kernel_launch(void* const* d_in, const int* in_sizes, int n_in,
                              void* d_out, int out_size, void* d_ws,
                              size_t ws_size, hipStream_t stream) {
  const float* x = (const float*)d_in[0];
  const float* cells = (const float*)d_in[1];
  const float* q_w = (const float*)d_in[2];
  const float* q_b = (const float*)d_in[3];
  const float* v = (const float*)d_in[4];
  const float* vb = (const float*)d_in[5];
  const float* ln_g = (const float*)d_in[6];
  const float* ln_b = (const float*)d_in[7];
  float* out = (float*)d_out;

  u16* hb = (u16*)d_ws;                            // 2 MB
  u16* htb = hb + (size_t)Bn * Ln * EMBn;          // 2 MB
  u16* Pb = htb + (size_t)Bn * Ln * EMBn;          // 256 KB
  u16* Wb = Pb + (size_t)Rn * EMBn;                // 1 MB
  float* pb = (float*)(Wb + (size_t)Bn * Rn * Ln); // 1 KB
  float* G = pb + Rn;                              // 2 MB

  ln_pproj_kernel<<<768, 256, 0, stream>>>(x, ln_g, ln_b, cells, q_w, q_b, hb,
                                           Pb, pb);
  score_sm_trans_kernel<<<320, 512, 0, stream>>>(hb, Pb, pb, htb, Wb);
  gmat_kernel<<<128, 256, 0, stream>>>(htb, Wb, G);
  out_kernel<<<1024, 256, 0, stream>>>(v, vb, G, out);
}